// Round 7
// baseline (420.074 us; speedup 1.0000x reference)
//
#include <hip/hip_runtime.h>
#include <hip/hip_bf16.h>

// ---------------- problem constants ----------------
constexpr int NN = 50000;     // nodes
constexpr int NE = 400000;    // edges (without self loops)
constexpr int NE2 = NE + NN;  // with self loops
constexpr float NEG_SLOPE = 0.2f;
constexpr float LOG2E = 1.44269504f;

typedef __attribute__((ext_vector_type(8))) __bf16 bf16x8;
typedef __attribute__((ext_vector_type(4))) float f32x4;

__device__ inline float bf2f(unsigned short u) { return __uint_as_float(((unsigned)u) << 16); }
__device__ inline unsigned short f2bf(float f) {
    unsigned x = __float_as_uint(f);
    return (unsigned short)((x + 0x7fffu + ((x >> 16) & 1u)) >> 16);  // RNE
}

__device__ inline void gload16(const unsigned short* g, unsigned short* l) {
    // async global->LDS, 16B per lane; LDS dest is wave-uniform base + lane*16
    __builtin_amdgcn_global_load_lds(
        (const __attribute__((address_space(1))) unsigned int*)(g),
        (__attribute__((address_space(3))) unsigned int*)(l), 16, 0, 0);
}

// ---------------- CSR build ----------------
__global__ void count_deg(const int* __restrict__ ei, int* __restrict__ deg) {
    int e = blockIdx.x * blockDim.x + threadIdx.x;
    if (e >= NE2) return;
    int dst = (e < NE) ? ei[NE + e] : (e - NE);
    atomicAdd(&deg[dst], 1);
}

// multi-block scan: local scan (coalesced, 1 elem/thread) -> block-sum scan -> offset add
constexpr int SCAN_NB = (NN + 1023) / 1024;  // 49

__global__ __launch_bounds__(1024) void scan_local(const int* __restrict__ deg,
                                                   int* __restrict__ row_ptr,
                                                   int* __restrict__ bsum) {
    __shared__ int wsum[16];
    const int t = threadIdx.x, lane = t & 63, w = t >> 6;
    const int i = blockIdx.x * 1024 + t;
    int v = (i < NN) ? deg[i] : 0;
    int x = v;
    #pragma unroll
    for (int off = 1; off < 64; off <<= 1) {
        int y = __shfl_up(x, off);
        if (lane >= off) x += y;
    }
    if (lane == 63) wsum[w] = x;
    __syncthreads();
    if (w == 0 && lane < 16) {
        int s = wsum[lane];
        #pragma unroll
        for (int off = 1; off < 16; off <<= 1) {
            int y = __shfl_up(s, off);
            if (lane >= off) s += y;
        }
        wsum[lane] = s;
    }
    __syncthreads();
    int excl = ((w == 0) ? 0 : wsum[w - 1]) + x - v;  // exclusive within block
    if (i < NN) row_ptr[i] = excl;
    if (t == 1023) bsum[blockIdx.x] = wsum[15];       // block total
}

__global__ void scan_bsums(int* __restrict__ bsum, int* __restrict__ row_ptr) {
    int lane = threadIdx.x;  // 64 threads, single wave
    int v = (lane < SCAN_NB) ? bsum[lane] : 0;
    int x = v;
    #pragma unroll
    for (int off = 1; off < 64; off <<= 1) {
        int y = __shfl_up(x, off);
        if (lane >= off) x += y;
    }
    if (lane < SCAN_NB) bsum[lane] = x - v;  // exclusive block offset
    if (lane == 63) row_ptr[NN] = x;         // grand total (= NE2)
}

__global__ __launch_bounds__(1024) void scan_add(int* __restrict__ row_ptr,
                                                 int* __restrict__ cursor,
                                                 const int* __restrict__ bsum) {
    const int i = blockIdx.x * 1024 + threadIdx.x;
    if (i < NN) {
        int e = row_ptr[i] + bsum[blockIdx.x];
        row_ptr[i] = e;
        cursor[i] = e;
    }
}

__global__ void scatter_edges(const int* __restrict__ ei, int* __restrict__ cursor,
                              int* __restrict__ csr_src) {
    int e = blockIdx.x * blockDim.x + threadIdx.x;
    if (e >= NE2) return;
    int src, dst;
    if (e < NE) { src = ei[e]; dst = ei[NE + e]; }
    else        { src = dst = e - NE; }
    int pos = atomicAdd(&cursor[dst], 1);
    csr_src[pos] = src;
}

// ---------------- fp32 -> bf16 convert (x) ----------------
__global__ void f32_to_bf16(const float* __restrict__ in, unsigned short* __restrict__ out, int n4) {
    int i = blockIdx.x * blockDim.x + threadIdx.x;
    if (i >= n4) return;
    float4 v = *(const float4*)(in + 4 * (size_t)i);
    ushort4 o;
    o.x = f2bf(v.x); o.y = f2bf(v.y); o.z = f2bf(v.z); o.w = f2bf(v.w);
    *(ushort4*)(out + 4 * (size_t)i) = o;
}

// ---------------- one-shot weight conversion: all 8 W matrices -> bf16, concatenated ----------------
__global__ void conv_weights(const float* __restrict__ w0l, const float* __restrict__ w0r,
                             const float* __restrict__ w1l, const float* __restrict__ w1r,
                             const float* __restrict__ w2l, const float* __restrict__ w2r,
                             const float* __restrict__ w3l, const float* __restrict__ w3r,
                             unsigned short* __restrict__ out) {
    int i = blockIdx.x * blockDim.x + threadIdx.x;  // float4 index, 0..98303
    const float* src; int base;
    if      (i < 8192)  { src = w0l; base = 0; }
    else if (i < 16384) { src = w0r; base = 8192; }
    else if (i < 32768) { src = w1l; base = 16384; }
    else if (i < 49152) { src = w1r; base = 32768; }
    else if (i < 65536) { src = w2l; base = 49152; }
    else if (i < 81920) { src = w2r; base = 65536; }
    else if (i < 90112) { src = w3l; base = 81920; }
    else                { src = w3r; base = 90112; }
    float4 v = ((const float4*)src)[i - base];
    ushort4 o;
    o.x = f2bf(v.x); o.y = f2bf(v.y); o.z = f2bf(v.z); o.w = f2bf(v.w);
    ((ushort4*)out)[i] = o;
}

// ---------------- fused bf16 MFMA GEMM: [xl | xr] = A @ [Wl;Wr]^T + bias ----------------
// Single-buffer (R2-proven). Swapped MFMA operands -> lane holds 4 consecutive
// out-cols -> ushort4 stores. Bijective XCD swizzle for A-tile L2 reuse.
#define GBM 128
#define GBN 128
#define GBK 64

__global__ __launch_bounds__(256) void gemm_fused(const unsigned short* __restrict__ A,
                                                  const unsigned short* __restrict__ Wc,
                                                  const float* __restrict__ bl,
                                                  const float* __restrict__ br,
                                                  unsigned short* __restrict__ outl,
                                                  unsigned short* __restrict__ outr,
                                                  int M, int Nhalf, int K, int lognx) {
    __shared__ __align__(16) unsigned short Alds[GBM * GBK];
    __shared__ __align__(16) unsigned short Wlds[GBN * GBK];
    // bijective XCD swizzle (m204): blocks sharing an A-tile land on the same XCD L2
    const int nwg = gridDim.x;
    const int q = nwg >> 3, r8 = nwg & 7;
    const int xcd = blockIdx.x & 7, off = blockIdx.x >> 3;
    const int wg = (xcd < r8 ? xcd * (q + 1) : r8 * (q + 1) + (xcd - r8) * q) + off;
    const int nx = 1 << lognx;
    const int bm = (wg >> lognx) * GBM, bn = (wg & (nx - 1)) * GBN;

    const int tid = threadIdx.x;
    const int lane = tid & 63, wave = tid >> 6;
    const int wr = wave >> 1, wc = wave & 1;       // wave -> 64x64 sub-tile
    const int lrow = lane & 15, kgrp = lane >> 4;  // fragment indices

    f32x4 acc[4][4] = {};

    for (int k0 = 0; k0 < K; k0 += GBK) {
        // stage A and W: 1024 16B chunks each, 4 per thread, direct to LDS
        #pragma unroll
        for (int i = 0; i < 4; ++i) {
            int p = i * 256 + tid;            // chunk id
            int r = p >> 3, ck = p & 7;       // row, chunk-in-row (8 chunks = 64 bf16)
            int sck = ck ^ (r & 7);           // inverse-swizzled source chunk
            int ga = bm + r; ga = (ga < M) ? ga : (M - 1);   // clamp tail (write-guarded)
            unsigned short* la = &Alds[(unsigned)(i * 256 + wave * 64) * 8];
            gload16(A + (size_t)ga * K + k0 + sck * 8, la);
            unsigned short* lw = &Wlds[(unsigned)(i * 256 + wave * 64) * 8];
            gload16(Wc + (size_t)(bn + r) * K + k0 + sck * 8, lw);
        }
        __syncthreads();
        #pragma unroll
        for (int kk = 0; kk < GBK; kk += 32) {
            bf16x8 av[4], bv[4];
            #pragma unroll
            for (int i = 0; i < 4; ++i) {
                int ar = wr * 64 + i * 16 + lrow;
                int ch = ((kk >> 3) + kgrp) ^ (ar & 7);
                av[i] = *(const bf16x8*)(&Alds[ar * GBK + ch * 8]);
            }
            #pragma unroll
            for (int j = 0; j < 4; ++j) {
                int brw = wc * 64 + j * 16 + lrow;
                int ch = ((kk >> 3) + kgrp) ^ (brw & 7);
                bv[j] = *(const bf16x8*)(&Wlds[brw * GBK + ch * 8]);
            }
            // swapped operands: D row-dim <- bv (out cols), col-dim <- av (out rows)
            #pragma unroll
            for (int i = 0; i < 4; ++i)
                #pragma unroll
                for (int j = 0; j < 4; ++j)
                    acc[i][j] = __builtin_amdgcn_mfma_f32_16x16x32_bf16(bv[j], av[i], acc[i][j], 0, 0, 0);
        }
        __syncthreads();
    }

    // epilogue: lane holds out[row = bm+wr*64+i*16+lrow][col = cb+j*16+kgrp*4+r], r=0..3
    const int half = (bn >= Nhalf) ? 1 : 0;
    unsigned short* outp = half ? outr : outl;
    const float* bp = half ? br : bl;
    const int cb = bn - half * Nhalf + wc * 64;
    #pragma unroll
    for (int i = 0; i < 4; ++i) {
        int row = bm + wr * 64 + i * 16 + lrow;
        if (row < M) {
            #pragma unroll
            for (int j = 0; j < 4; ++j) {
                int col = cb + j * 16 + kgrp * 4;
                float4 bb = *(const float4*)(bp + col);
                ushort4 o;
                o.x = f2bf(acc[i][j][0] + bb.x);
                o.y = f2bf(acc[i][j][1] + bb.y);
                o.z = f2bf(acc[i][j][2] + bb.z);
                o.w = f2bf(acc[i][j][3] + bb.w);
                *(ushort4*)(outp + (size_t)row * Nhalf + col) = o;
            }
        }
    }
}

// ---------------- fused GATv2 edge kernel (VEC=4, NW full-wave slices/node, LDS merge) ----------------
// R2-proven shape (2 waves/node, 69% occupancy) + 4-deep edge groups (in-wave MLP),
// defer-max rescale, exp2-domain logits.
template <int H, int C, int NW, bool DO_ELU, bool DO_RES, bool OUT_F32>
__global__ __launch_bounds__(128) void gat_edge4(
        const unsigned short* __restrict__ xl,
        const unsigned short* __restrict__ xr,
        const float* __restrict__ att, const float* __restrict__ bias,
        const unsigned short* __restrict__ res, void* __restrict__ outp,
        const int* __restrict__ row_ptr, const int* __restrict__ csr_src) {
    constexpr int HC = H * C;
    constexpr int T = HC / 4;      // lanes per slice (64 or 32)
    constexpr int RW = C / 4;      // lanes per head-reduce group (8 or 32)
    constexpr float THR = 11.54f;  // defer-max threshold (log2 domain, = 8/ln2)
    __shared__ float smem[NW * T * 6];

    const int n = blockIdx.x;
    const int tid = threadIdx.x;   // block = NW*T = 128 threads
    const int w = tid / T;         // slice id (wave-aligned: T is 64 or 32)
    const int t = tid % T;
    const int ch = 4 * t;
    const size_t base_r = (size_t)n * HC + ch;

    float xr4[4], av[4], acc[4] = {0.f, 0.f, 0.f, 0.f};
    {
        ushort4 u = *(const ushort4*)(xr + base_r);
        xr4[0] = bf2f(u.x); xr4[1] = bf2f(u.y); xr4[2] = bf2f(u.z); xr4[3] = bf2f(u.w);
        float4 a = *(const float4*)(att + ch);
        av[0] = a.x * LOG2E; av[1] = a.y * LOG2E; av[2] = a.z * LOG2E; av[3] = a.w * LOG2E;
    }

    float m = -1e30f, d = 0.f;
    const int beg = row_ptr[n], end = row_ptr[n + 1];
    const int nmain = (end - beg) / (4 * NW);

    // ---- main: 4-deep contiguous edge groups per slice ----
    for (int g = 0; g < nmain; ++g) {
        const int base = beg + (g * NW + w) * 4;
        int s[4];
        #pragma unroll
        for (int k = 0; k < 4; ++k) s[k] = csr_src[base + k];
        ushort4 gx[4];
        #pragma unroll
        for (int k = 0; k < 4; ++k) gx[k] = *(const ushort4*)(xl + (size_t)s[k] * HC + ch);
        float xv[4][4], p[4];
        #pragma unroll
        for (int k = 0; k < 4; ++k) {
            xv[k][0] = bf2f(gx[k].x); xv[k][1] = bf2f(gx[k].y);
            xv[k][2] = bf2f(gx[k].z); xv[k][3] = bf2f(gx[k].w);
            float pp = 0.f;
            #pragma unroll
            for (int q = 0; q < 4; ++q) {
                float u = xv[k][q] + xr4[q];
                u = fmaxf(u, u * NEG_SLOPE);
                pp = fmaf(u, av[q], pp);
            }
            p[k] = pp;
        }
        #pragma unroll
        for (int mm = RW / 2; mm >= 1; mm >>= 1) {
            #pragma unroll
            for (int k = 0; k < 4; ++k) p[k] += __shfl_xor(p[k], mm);
        }
        float pmax = fmaxf(fmaxf(p[0], p[1]), fmaxf(p[2], p[3]));
        if (__any(pmax > m + THR)) {
            float mn = fmaxf(m, pmax);
            float sc = exp2f(m - mn);
            float e0 = exp2f(p[0] - mn), e1 = exp2f(p[1] - mn);
            float e2 = exp2f(p[2] - mn), e3 = exp2f(p[3] - mn);
            d = d * sc + (e0 + e1) + (e2 + e3);
            #pragma unroll
            for (int q = 0; q < 4; ++q)
                acc[q] = acc[q] * sc + (xv[0][q] * e0 + xv[1][q] * e1)
                                     + (xv[2][q] * e2 + xv[3][q] * e3);
            m = mn;
        } else {
            float e0 = exp2f(p[0] - m), e1 = exp2f(p[1] - m);
            float e2 = exp2f(p[2] - m), e3 = exp2f(p[3] - m);
            d += (e0 + e1) + (e2 + e3);
            #pragma unroll
            for (int q = 0; q < 4; ++q)
                acc[q] += (xv[0][q] * e0 + xv[1][q] * e1) + (xv[2][q] * e2 + xv[3][q] * e3);
        }
    }

    // ---- tail: pairwise then single, interleaved by slice ----
    int e = beg + nmain * 4 * NW + w;
    for (; e + NW < end; e += 2 * NW) {
        int s0 = csr_src[e], s1 = csr_src[e + NW];
        ushort4 g0 = *(const ushort4*)(xl + (size_t)s0 * HC + ch);
        ushort4 g1 = *(const ushort4*)(xl + (size_t)s1 * HC + ch);
        float x0[4], x1[4];
        x0[0] = bf2f(g0.x); x0[1] = bf2f(g0.y); x0[2] = bf2f(g0.z); x0[3] = bf2f(g0.w);
        x1[0] = bf2f(g1.x); x1[1] = bf2f(g1.y); x1[2] = bf2f(g1.z); x1[3] = bf2f(g1.w);
        float p0 = 0.f, p1 = 0.f;
        #pragma unroll
        for (int q = 0; q < 4; ++q) {
            float u0 = x0[q] + xr4[q]; u0 = fmaxf(u0, u0 * NEG_SLOPE); p0 = fmaf(u0, av[q], p0);
            float u1 = x1[q] + xr4[q]; u1 = fmaxf(u1, u1 * NEG_SLOPE); p1 = fmaf(u1, av[q], p1);
        }
        #pragma unroll
        for (int mm = RW / 2; mm >= 1; mm >>= 1) {
            p0 += __shfl_xor(p0, mm);
            p1 += __shfl_xor(p1, mm);
        }
        float pmax = fmaxf(p0, p1);
        if (__any(pmax > m + THR)) {
            float mn = fmaxf(m, pmax);
            float sc = exp2f(m - mn);
            float e0 = exp2f(p0 - mn), e1 = exp2f(p1 - mn);
            d = d * sc + e0 + e1;
            #pragma unroll
            for (int q = 0; q < 4; ++q) acc[q] = acc[q] * sc + x0[q] * e0 + x1[q] * e1;
            m = mn;
        } else {
            float e0 = exp2f(p0 - m), e1 = exp2f(p1 - m);
            d += e0 + e1;
            #pragma unroll
            for (int q = 0; q < 4; ++q) acc[q] += x0[q] * e0 + x1[q] * e1;
        }
    }
    if (e < end) {  // final single edge (at most one per slice)
        int s0 = csr_src[e];
        ushort4 g0 = *(const ushort4*)(xl + (size_t)s0 * HC + ch);
        float x0[4];
        x0[0] = bf2f(g0.x); x0[1] = bf2f(g0.y); x0[2] = bf2f(g0.z); x0[3] = bf2f(g0.w);
        float p0 = 0.f;
        #pragma unroll
        for (int q = 0; q < 4; ++q) {
            float u0 = x0[q] + xr4[q]; u0 = fmaxf(u0, u0 * NEG_SLOPE); p0 = fmaf(u0, av[q], p0);
        }
        #pragma unroll
        for (int mm = RW / 2; mm >= 1; mm >>= 1) p0 += __shfl_xor(p0, mm);
        if (__any(p0 > m + THR)) {
            float mn = fmaxf(m, p0);
            float sc = exp2f(m - mn);
            float e0 = exp2f(p0 - mn);
            d = d * sc + e0;
            #pragma unroll
            for (int q = 0; q < 4; ++q) acc[q] = acc[q] * sc + x0[q] * e0;
            m = mn;
        } else {
            float e0 = exp2f(p0 - m);
            d += e0;
            #pragma unroll
            for (int q = 0; q < 4; ++q) acc[q] += x0[q] * e0;
        }
    }

    // ---- cross-slice online-softmax merge via LDS (R2-proven) ----
    float* st = &smem[(w * T + t) * 6];
    st[0] = m; st[1] = d;
    st[2] = acc[0]; st[3] = acc[1]; st[4] = acc[2]; st[5] = acc[3];
    __syncthreads();
    if (w == 0) {
        #pragma unroll
        for (int o = 1; o < NW; ++o) {
            const float* so = &smem[(o * T + t) * 6];
            float mo = so[0], dd = so[1];
            float mn = fmaxf(m, mo);
            float s0 = exp2f(m - mn), s1 = exp2f(mo - mn);
            d = d * s0 + dd * s1;
            #pragma unroll
            for (int q = 0; q < 4; ++q) acc[q] = acc[q] * s0 + so[2 + q] * s1;
            m = mn;
        }
        float inv = 1.f / d;  // >=1 edge guaranteed (self loop)
        float4 b = *(const float4*)(bias + ch);
        float o0 = acc[0] * inv + b.x, o1 = acc[1] * inv + b.y;
        float o2 = acc[2] * inv + b.z, o3 = acc[3] * inv + b.w;
        if constexpr (DO_ELU) {
            o0 = o0 > 0.f ? o0 : exp2f(o0 * LOG2E) - 1.f;
            o1 = o1 > 0.f ? o1 : exp2f(o1 * LOG2E) - 1.f;
            o2 = o2 > 0.f ? o2 : exp2f(o2 * LOG2E) - 1.f;
            o3 = o3 > 0.f ? o3 : exp2f(o3 * LOG2E) - 1.f;
        }
        if constexpr (DO_RES) {
            ushort4 ru = *(const ushort4*)(res + base_r);
            o0 += bf2f(ru.x); o1 += bf2f(ru.y); o2 += bf2f(ru.z); o3 += bf2f(ru.w);
        }
        if constexpr (OUT_F32) {
            *(float4*)((float*)outp + base_r) = make_float4(o0, o1, o2, o3);
        } else {
            ushort4 u;
            u.x = f2bf(o0); u.y = f2bf(o1); u.z = f2bf(o2); u.w = f2bf(o3);
            *(ushort4*)((unsigned short*)outp + base_r) = u;
        }
    }
}

// ---------------- host orchestration ----------------
extern "C" void kernel_launch(void* const* d_in, const int* in_sizes, int n_in,
                              void* d_out, int out_size, void* d_ws, size_t ws_size,
                              hipStream_t stream) {
    const float* x  = (const float*)d_in[0];
    const int*   ei = (const int*)d_in[1];
    auto P = [&](int layer, int j) { return (const float*)d_in[2 + 6 * layer + j]; };

    unsigned short* x_bf = (unsigned short*)d_ws;              // [NN][128]
    unsigned short* h0 = x_bf + (size_t)NN * 128;              // [NN][256]
    unsigned short* h1 = h0 + (size_t)NN * 256;                // [NN][256]
    unsigned short* xl = h1 + (size_t)NN * 256;                // [NN][256]
    unsigned short* xr = xl + (size_t)NN * 256;                // [NN][256]
    unsigned short* Wb = xr + (size_t)NN * 256;                // 393216 bf16 (all weights)
    int* csr_src = (int*)(Wb + 393216);                        // [NE2]
    int* row_ptr = csr_src + NE2;
    int* cursor  = row_ptr + (NN + 1);
    int* deg     = cursor + NN;
    int* bsum    = deg + NN;                                   // [SCAN_NB]

    // ---- CSR build ----
    hipMemsetAsync(deg, 0, NN * sizeof(int), stream);
    int eb = (NE2 + 255) / 256;
    count_deg<<<eb, 256, 0, stream>>>(ei, deg);
    scan_local<<<SCAN_NB, 1024, 0, stream>>>(deg, row_ptr, bsum);
    scan_bsums<<<1, 64, 0, stream>>>(bsum, row_ptr);
    scan_add<<<SCAN_NB, 1024, 0, stream>>>(row_ptr, cursor, bsum);
    scatter_edges<<<eb, 256, 0, stream>>>(ei, cursor, csr_src);

    // ---- one-shot conversions ----
    conv_weights<<<384, 256, 0, stream>>>(P(0, 0), P(0, 2), P(1, 0), P(1, 2),
                                          P(2, 0), P(2, 2), P(3, 0), P(3, 2), Wb);
    int n4 = NN * 128 / 4;
    f32_to_bf16<<<(n4 + 255) / 256, 256, 0, stream>>>(x, x_bf, n4);

    const int mb = (NN + GBM - 1) / GBM;     // 391
    const int nwgL = 4 * mb, nwgLast = 2 * mb;

    // ---- Layer 0: 128 -> 8x32, ELU, no residual ----
    gemm_fused<<<nwgL, 256, 0, stream>>>(x_bf, Wb + 0,      P(0, 1), P(0, 3), xl, xr, NN, 256, 128, 2);
    gat_edge4<8, 32, 2, true, false, false><<<NN, 128, 0, stream>>>(xl, xr, P(0, 4), P(0, 5),
                                                                    nullptr, h0, row_ptr, csr_src);
    // ---- Layer 1 ----
    gemm_fused<<<nwgL, 256, 0, stream>>>(h0,   Wb + 65536,  P(1, 1), P(1, 3), xl, xr, NN, 256, 256, 2);
    gat_edge4<8, 32, 2, true, true, false><<<NN, 128, 0, stream>>>(xl, xr, P(1, 4), P(1, 5),
                                                                   h0, h1, row_ptr, csr_src);
    // ---- Layer 2 ----
    gemm_fused<<<nwgL, 256, 0, stream>>>(h1,   Wb + 196608, P(2, 1), P(2, 3), xl, xr, NN, 256, 256, 2);
    gat_edge4<8, 32, 2, true, true, false><<<NN, 128, 0, stream>>>(xl, xr, P(2, 4), P(2, 5),
                                                                   h1, h0, row_ptr, csr_src);
    // ---- Layer 3: 256 -> 1x128, output fp32 ----
    gemm_fused<<<nwgLast, 256, 0, stream>>>(h0, Wb + 327680, P(3, 1), P(3, 3), xl, xr, NN, 128, 256, 1);
    gat_edge4<1, 128, 4, false, false, true><<<NN, 128, 0, stream>>>(xl, xr, P(3, 4), P(3, 5),
                                                                     nullptr, d_out, row_ptr, csr_src);
}

// Round 8
// 397.983 us; speedup vs baseline: 1.0555x; 1.0555x over previous
//
#include <hip/hip_runtime.h>
#include <hip/hip_bf16.h>

// ---------------- problem constants ----------------
constexpr int NN = 50000;     // nodes
constexpr int NE = 400000;    // edges (without self loops)
constexpr int NE2 = NE + NN;  // with self loops
constexpr float NEG_SLOPE = 0.2f;
constexpr float LOG2E = 1.44269504f;

typedef __attribute__((ext_vector_type(8))) __bf16 bf16x8;
typedef __attribute__((ext_vector_type(4))) float f32x4;

__device__ inline float bf2f(unsigned short u) { return __uint_as_float(((unsigned)u) << 16); }
__device__ inline unsigned short f2bf(float f) {
    unsigned x = __float_as_uint(f);
    return (unsigned short)((x + 0x7fffu + ((x >> 16) & 1u)) >> 16);  // RNE
}

__device__ inline void gload16(const unsigned short* g, unsigned short* l) {
    // async global->LDS, 16B per lane; LDS dest is wave-uniform base + lane*16
    __builtin_amdgcn_global_load_lds(
        (const __attribute__((address_space(1))) unsigned int*)(g),
        (__attribute__((address_space(3))) unsigned int*)(l), 16, 0, 0);
}

// ---------------- CSR build ----------------
__global__ void count_deg(const int* __restrict__ ei, int* __restrict__ deg) {
    int e = blockIdx.x * blockDim.x + threadIdx.x;
    if (e >= NE2) return;
    int dst = (e < NE) ? ei[NE + e] : (e - NE);
    atomicAdd(&deg[dst], 1);
}

// multi-block scan: local scan (coalesced, 1 elem/thread) -> block-sum scan -> offset add
constexpr int SCAN_NB = (NN + 1023) / 1024;  // 49

__global__ __launch_bounds__(1024) void scan_local(const int* __restrict__ deg,
                                                   int* __restrict__ row_ptr,
                                                   int* __restrict__ bsum) {
    __shared__ int wsum[16];
    const int t = threadIdx.x, lane = t & 63, w = t >> 6;
    const int i = blockIdx.x * 1024 + t;
    int v = (i < NN) ? deg[i] : 0;
    int x = v;
    #pragma unroll
    for (int off = 1; off < 64; off <<= 1) {
        int y = __shfl_up(x, off);
        if (lane >= off) x += y;
    }
    if (lane == 63) wsum[w] = x;
    __syncthreads();
    if (w == 0 && lane < 16) {
        int s = wsum[lane];
        #pragma unroll
        for (int off = 1; off < 16; off <<= 1) {
            int y = __shfl_up(s, off);
            if (lane >= off) s += y;
        }
        wsum[lane] = s;
    }
    __syncthreads();
    int excl = ((w == 0) ? 0 : wsum[w - 1]) + x - v;  // exclusive within block
    if (i < NN) row_ptr[i] = excl;
    if (t == 1023) bsum[blockIdx.x] = wsum[15];       // block total
}

__global__ void scan_bsums(int* __restrict__ bsum, int* __restrict__ row_ptr) {
    int lane = threadIdx.x;  // 64 threads, single wave
    int v = (lane < SCAN_NB) ? bsum[lane] : 0;
    int x = v;
    #pragma unroll
    for (int off = 1; off < 64; off <<= 1) {
        int y = __shfl_up(x, off);
        if (lane >= off) x += y;
    }
    if (lane < SCAN_NB) bsum[lane] = x - v;  // exclusive block offset
    if (lane == 63) row_ptr[NN] = x;         // grand total (= NE2)
}

__global__ __launch_bounds__(1024) void scan_add(int* __restrict__ row_ptr,
                                                 int* __restrict__ cursor,
                                                 const int* __restrict__ bsum) {
    const int i = blockIdx.x * 1024 + threadIdx.x;
    if (i < NN) {
        int e = row_ptr[i] + bsum[blockIdx.x];
        row_ptr[i] = e;
        cursor[i] = e;
    }
}

__global__ void scatter_edges(const int* __restrict__ ei, int* __restrict__ cursor,
                              int* __restrict__ csr_src) {
    int e = blockIdx.x * blockDim.x + threadIdx.x;
    if (e >= NE2) return;
    int src, dst;
    if (e < NE) { src = ei[e]; dst = ei[NE + e]; }
    else        { src = dst = e - NE; }
    int pos = atomicAdd(&cursor[dst], 1);
    csr_src[pos] = src;
}

// ---------------- fp32 -> bf16 convert (x) ----------------
__global__ void f32_to_bf16(const float* __restrict__ in, unsigned short* __restrict__ out, int n4) {
    int i = blockIdx.x * blockDim.x + threadIdx.x;
    if (i >= n4) return;
    float4 v = *(const float4*)(in + 4 * (size_t)i);
    ushort4 o;
    o.x = f2bf(v.x); o.y = f2bf(v.y); o.z = f2bf(v.z); o.w = f2bf(v.w);
    *(ushort4*)(out + 4 * (size_t)i) = o;
}

// ---------------- one-shot weight conversion: all 8 W matrices -> bf16, concatenated ----------------
__global__ void conv_weights(const float* __restrict__ w0l, const float* __restrict__ w0r,
                             const float* __restrict__ w1l, const float* __restrict__ w1r,
                             const float* __restrict__ w2l, const float* __restrict__ w2r,
                             const float* __restrict__ w3l, const float* __restrict__ w3r,
                             unsigned short* __restrict__ out) {
    int i = blockIdx.x * blockDim.x + threadIdx.x;  // float4 index, 0..98303
    const float* src; int base;
    if      (i < 8192)  { src = w0l; base = 0; }
    else if (i < 16384) { src = w0r; base = 8192; }
    else if (i < 32768) { src = w1l; base = 16384; }
    else if (i < 49152) { src = w1r; base = 32768; }
    else if (i < 65536) { src = w2l; base = 49152; }
    else if (i < 81920) { src = w2r; base = 65536; }
    else if (i < 90112) { src = w3l; base = 81920; }
    else                { src = w3r; base = 90112; }
    float4 v = ((const float4*)src)[i - base];
    ushort4 o;
    o.x = f2bf(v.x); o.y = f2bf(v.y); o.z = f2bf(v.z); o.w = f2bf(v.w);
    ((ushort4*)out)[i] = o;
}

// ---------------- fused bf16 MFMA GEMM: [xl | xr] = A @ [Wl;Wr]^T + bias ----------------
// Single-buffer (proven; dbuf measured neutral R3/R4). Swapped MFMA operands ->
// lane holds 4 consecutive out-cols -> ushort4 stores. Bijective XCD swizzle.
#define GBM 128
#define GBN 128
#define GBK 64

__global__ __launch_bounds__(256) void gemm_fused(const unsigned short* __restrict__ A,
                                                  const unsigned short* __restrict__ Wc,
                                                  const float* __restrict__ bl,
                                                  const float* __restrict__ br,
                                                  unsigned short* __restrict__ outl,
                                                  unsigned short* __restrict__ outr,
                                                  int M, int Nhalf, int K, int lognx) {
    __shared__ __align__(16) unsigned short Alds[GBM * GBK];
    __shared__ __align__(16) unsigned short Wlds[GBN * GBK];
    // bijective XCD swizzle (m204): blocks sharing an A-tile land on the same XCD L2
    const int nwg = gridDim.x;
    const int q = nwg >> 3, r8 = nwg & 7;
    const int xcd = blockIdx.x & 7, off = blockIdx.x >> 3;
    const int wg = (xcd < r8 ? xcd * (q + 1) : r8 * (q + 1) + (xcd - r8) * q) + off;
    const int nx = 1 << lognx;
    const int bm = (wg >> lognx) * GBM, bn = (wg & (nx - 1)) * GBN;

    const int tid = threadIdx.x;
    const int lane = tid & 63, wave = tid >> 6;
    const int wr = wave >> 1, wc = wave & 1;       // wave -> 64x64 sub-tile
    const int lrow = lane & 15, kgrp = lane >> 4;  // fragment indices

    f32x4 acc[4][4] = {};

    for (int k0 = 0; k0 < K; k0 += GBK) {
        // stage A and W: 1024 16B chunks each, 4 per thread, direct to LDS
        #pragma unroll
        for (int i = 0; i < 4; ++i) {
            int p = i * 256 + tid;            // chunk id
            int r = p >> 3, ck = p & 7;       // row, chunk-in-row (8 chunks = 64 bf16)
            int sck = ck ^ (r & 7);           // inverse-swizzled source chunk
            int ga = bm + r; ga = (ga < M) ? ga : (M - 1);   // clamp tail (write-guarded)
            unsigned short* la = &Alds[(unsigned)(i * 256 + wave * 64) * 8];
            gload16(A + (size_t)ga * K + k0 + sck * 8, la);
            unsigned short* lw = &Wlds[(unsigned)(i * 256 + wave * 64) * 8];
            gload16(Wc + (size_t)(bn + r) * K + k0 + sck * 8, lw);
        }
        __syncthreads();
        #pragma unroll
        for (int kk = 0; kk < GBK; kk += 32) {
            bf16x8 av[4], bv[4];
            #pragma unroll
            for (int i = 0; i < 4; ++i) {
                int ar = wr * 64 + i * 16 + lrow;
                int ch = ((kk >> 3) + kgrp) ^ (ar & 7);
                av[i] = *(const bf16x8*)(&Alds[ar * GBK + ch * 8]);
            }
            #pragma unroll
            for (int j = 0; j < 4; ++j) {
                int brw = wc * 64 + j * 16 + lrow;
                int ch = ((kk >> 3) + kgrp) ^ (brw & 7);
                bv[j] = *(const bf16x8*)(&Wlds[brw * GBK + ch * 8]);
            }
            // swapped operands: D row-dim <- bv (out cols), col-dim <- av (out rows)
            #pragma unroll
            for (int i = 0; i < 4; ++i)
                #pragma unroll
                for (int j = 0; j < 4; ++j)
                    acc[i][j] = __builtin_amdgcn_mfma_f32_16x16x32_bf16(bv[j], av[i], acc[i][j], 0, 0, 0);
        }
        __syncthreads();
    }

    // epilogue: lane holds out[row = bm+wr*64+i*16+lrow][col = cb+j*16+kgrp*4+r], r=0..3
    const int half = (bn >= Nhalf) ? 1 : 0;
    unsigned short* outp = half ? outr : outl;
    const float* bp = half ? br : bl;
    const int cb = bn - half * Nhalf + wc * 64;
    #pragma unroll
    for (int i = 0; i < 4; ++i) {
        int row = bm + wr * 64 + i * 16 + lrow;
        if (row < M) {
            #pragma unroll
            for (int j = 0; j < 4; ++j) {
                int col = cb + j * 16 + kgrp * 4;
                float4 bb = *(const float4*)(bp + col);
                ushort4 o;
                o.x = f2bf(acc[i][j][0] + bb.x);
                o.y = f2bf(acc[i][j][1] + bb.y);
                o.z = f2bf(acc[i][j][2] + bb.z);
                o.w = f2bf(acc[i][j][3] + bb.w);
                *(ushort4*)(outp + (size_t)row * Nhalf + col) = o;
            }
        }
    }
}

// ---------------- fused GATv2 edge kernel (exact R2 structure + exp2-domain) ----------------
// VEC=4 channels/thread, NW slices of T=HC/4 lanes, simple pairwise edge loop,
// online-softmax merge via LDS. Proven 57us shape — do not restructure.
template <int H, int C, int NW, bool DO_ELU, bool DO_RES, bool OUT_F32>
__global__ __launch_bounds__(128) void gat_edge(
        const unsigned short* __restrict__ xl,
        const unsigned short* __restrict__ xr,
        const float* __restrict__ att, const float* __restrict__ bias,
        const unsigned short* __restrict__ res, void* __restrict__ outp,
        const int* __restrict__ row_ptr, const int* __restrict__ csr_src) {
    constexpr int HC = H * C;
    constexpr int T = HC / 4;      // lanes per slice
    constexpr int RW = C / 4;      // lanes per head (shfl-reduce group)
    __shared__ float smem[NW * T * 6];
    const int n = blockIdx.x;
    const int w = threadIdx.x / T;       // slice id
    const int t = threadIdx.x % T;       // lane within slice
    const int ch = 4 * t;
    const size_t base_r = (size_t)n * HC + ch;

    float xr4[4], av[4];
    {
        ushort4 u = *(const ushort4*)(xr + base_r);
        xr4[0] = bf2f(u.x); xr4[1] = bf2f(u.y); xr4[2] = bf2f(u.z); xr4[3] = bf2f(u.w);
        float4 a = *(const float4*)(att + ch);
        av[0] = a.x * LOG2E; av[1] = a.y * LOG2E;   // exp2-domain: fold log2e into att
        av[2] = a.z * LOG2E; av[3] = a.w * LOG2E;
    }

    float m = -1e30f, d = 0.f, acc[4] = {0.f, 0.f, 0.f, 0.f};

    const int beg = row_ptr[n], end = row_ptr[n + 1];
    int e = beg + w;
    for (; e + NW < end; e += 2 * NW) {
        int s0 = csr_src[e], s1 = csr_src[e + NW];
        ushort4 u0 = *(const ushort4*)(xl + (size_t)s0 * HC + ch);
        ushort4 u1 = *(const ushort4*)(xl + (size_t)s1 * HC + ch);
        float x0[4], x1[4];
        x0[0] = bf2f(u0.x); x0[1] = bf2f(u0.y); x0[2] = bf2f(u0.z); x0[3] = bf2f(u0.w);
        x1[0] = bf2f(u1.x); x1[1] = bf2f(u1.y); x1[2] = bf2f(u1.z); x1[3] = bf2f(u1.w);
        float p0 = 0.f, p1 = 0.f;
        #pragma unroll
        for (int v = 0; v < 4; ++v) {
            float a0 = x0[v] + xr4[v]; a0 = fmaxf(a0, a0 * NEG_SLOPE);
            float a1 = x1[v] + xr4[v]; a1 = fmaxf(a1, a1 * NEG_SLOPE);
            p0 = fmaf(a0, av[v], p0);
            p1 = fmaf(a1, av[v], p1);
        }
        #pragma unroll
        for (int mm = RW / 2; mm >= 1; mm >>= 1) {
            p0 += __shfl_xor(p0, mm);
            p1 += __shfl_xor(p1, mm);
        }
        float mn = fmaxf(m, fmaxf(p0, p1));
        float sc = exp2f(m - mn), e0 = exp2f(p0 - mn), e1 = exp2f(p1 - mn);
        d = d * sc + e0 + e1;
        #pragma unroll
        for (int v = 0; v < 4; ++v)
            acc[v] = fmaf(acc[v], sc, fmaf(e0, x0[v], e1 * x1[v]));
        m = mn;
    }
    if (e < end) {  // tail edge (at most one per slice)
        int s0 = csr_src[e];
        ushort4 u0 = *(const ushort4*)(xl + (size_t)s0 * HC + ch);
        float x0[4];
        x0[0] = bf2f(u0.x); x0[1] = bf2f(u0.y); x0[2] = bf2f(u0.z); x0[3] = bf2f(u0.w);
        float p0 = 0.f;
        #pragma unroll
        for (int v = 0; v < 4; ++v) {
            float a0 = x0[v] + xr4[v]; a0 = fmaxf(a0, a0 * NEG_SLOPE);
            p0 = fmaf(a0, av[v], p0);
        }
        #pragma unroll
        for (int mm = RW / 2; mm >= 1; mm >>= 1) p0 += __shfl_xor(p0, mm);
        float mn = fmaxf(m, p0);
        float sc = exp2f(m - mn), e0 = exp2f(p0 - mn);
        d = d * sc + e0;
        #pragma unroll
        for (int v = 0; v < 4; ++v) acc[v] = fmaf(acc[v], sc, e0 * x0[v]);
        m = mn;
    }

    // cross-slice online-softmax merge via LDS
    float* st = &smem[(w * T + t) * 6];
    st[0] = m; st[1] = d;
    st[2] = acc[0]; st[3] = acc[1]; st[4] = acc[2]; st[5] = acc[3];
    __syncthreads();
    if (w == 0) {
        #pragma unroll
        for (int o = 1; o < NW; ++o) {
            const float* so = &smem[(o * T + t) * 6];
            float mo = so[0], dd = so[1];
            float mn = fmaxf(m, mo);
            float s0 = exp2f(m - mn), s1 = exp2f(mo - mn);
            d = d * s0 + dd * s1;
            #pragma unroll
            for (int v = 0; v < 4; ++v) acc[v] = acc[v] * s0 + so[2 + v] * s1;
            m = mn;
        }
        float inv = 1.f / d;  // >=1 edge guaranteed (self loop in slice 0)
        float4 b = *(const float4*)(bias + ch);
        float o0 = acc[0] * inv + b.x, o1 = acc[1] * inv + b.y;
        float o2 = acc[2] * inv + b.z, o3 = acc[3] * inv + b.w;
        if constexpr (DO_ELU) {
            o0 = o0 > 0.f ? o0 : exp2f(o0 * LOG2E) - 1.f;
            o1 = o1 > 0.f ? o1 : exp2f(o1 * LOG2E) - 1.f;
            o2 = o2 > 0.f ? o2 : exp2f(o2 * LOG2E) - 1.f;
            o3 = o3 > 0.f ? o3 : exp2f(o3 * LOG2E) - 1.f;
        }
        if constexpr (DO_RES) {
            ushort4 ru = *(const ushort4*)(res + base_r);
            o0 += bf2f(ru.x); o1 += bf2f(ru.y); o2 += bf2f(ru.z); o3 += bf2f(ru.w);
        }
        if constexpr (OUT_F32) {
            *(float4*)((float*)outp + base_r) = make_float4(o0, o1, o2, o3);
        } else {
            ushort4 u;
            u.x = f2bf(o0); u.y = f2bf(o1); u.z = f2bf(o2); u.w = f2bf(o3);
            *(ushort4*)((unsigned short*)outp + base_r) = u;
        }
    }
}

// ---------------- host orchestration ----------------
extern "C" void kernel_launch(void* const* d_in, const int* in_sizes, int n_in,
                              void* d_out, int out_size, void* d_ws, size_t ws_size,
                              hipStream_t stream) {
    const float* x  = (const float*)d_in[0];
    const int*   ei = (const int*)d_in[1];
    auto P = [&](int layer, int j) { return (const float*)d_in[2 + 6 * layer + j]; };

    unsigned short* x_bf = (unsigned short*)d_ws;              // [NN][128]
    unsigned short* h0 = x_bf + (size_t)NN * 128;              // [NN][256]
    unsigned short* h1 = h0 + (size_t)NN * 256;                // [NN][256]
    unsigned short* xl = h1 + (size_t)NN * 256;                // [NN][256]
    unsigned short* xr = xl + (size_t)NN * 256;                // [NN][256]
    unsigned short* Wb = xr + (size_t)NN * 256;                // 393216 bf16 (all weights)
    int* csr_src = (int*)(Wb + 393216);                        // [NE2]
    int* row_ptr = csr_src + NE2;
    int* cursor  = row_ptr + (NN + 1);
    int* deg     = cursor + NN;
    int* bsum    = deg + NN;                                   // [SCAN_NB]

    // ---- CSR build ----
    hipMemsetAsync(deg, 0, NN * sizeof(int), stream);
    int eb = (NE2 + 255) / 256;
    count_deg<<<eb, 256, 0, stream>>>(ei, deg);
    scan_local<<<SCAN_NB, 1024, 0, stream>>>(deg, row_ptr, bsum);
    scan_bsums<<<1, 64, 0, stream>>>(bsum, row_ptr);
    scan_add<<<SCAN_NB, 1024, 0, stream>>>(row_ptr, cursor, bsum);
    scatter_edges<<<eb, 256, 0, stream>>>(ei, cursor, csr_src);

    // ---- one-shot conversions ----
    conv_weights<<<384, 256, 0, stream>>>(P(0, 0), P(0, 2), P(1, 0), P(1, 2),
                                          P(2, 0), P(2, 2), P(3, 0), P(3, 2), Wb);
    int n4 = NN * 128 / 4;
    f32_to_bf16<<<(n4 + 255) / 256, 256, 0, stream>>>(x, x_bf, n4);

    const int mb = (NN + GBM - 1) / GBM;     // 391
    const int nwgL = 4 * mb, nwgLast = 2 * mb;

    // ---- Layer 0: 128 -> 8x32, ELU, no residual ----
    gemm_fused<<<nwgL, 256, 0, stream>>>(x_bf, Wb + 0,      P(0, 1), P(0, 3), xl, xr, NN, 256, 128, 2);
    gat_edge<8, 32, 2, true, false, false><<<NN, 128, 0, stream>>>(xl, xr, P(0, 4), P(0, 5),
                                                                   nullptr, h0, row_ptr, csr_src);
    // ---- Layer 1 ----
    gemm_fused<<<nwgL, 256, 0, stream>>>(h0,   Wb + 65536,  P(1, 1), P(1, 3), xl, xr, NN, 256, 256, 2);
    gat_edge<8, 32, 2, true, true, false><<<NN, 128, 0, stream>>>(xl, xr, P(1, 4), P(1, 5),
                                                                  h0, h1, row_ptr, csr_src);
    // ---- Layer 2 ----
    gemm_fused<<<nwgL, 256, 0, stream>>>(h1,   Wb + 196608, P(2, 1), P(2, 3), xl, xr, NN, 256, 256, 2);
    gat_edge<8, 32, 2, true, true, false><<<NN, 128, 0, stream>>>(xl, xr, P(2, 4), P(2, 5),
                                                                  h1, h0, row_ptr, csr_src);
    // ---- Layer 3: 256 -> 1x128, output fp32 ----
    gemm_fused<<<nwgLast, 256, 0, stream>>>(h0, Wb + 327680, P(3, 1), P(3, 3), xl, xr, NN, 128, 256, 1);
    gat_edge<1, 128, 4, false, false, true><<<NN, 128, 0, stream>>>(xl, xr, P(3, 4), P(3, 5),
                                                                    nullptr, d_out, row_ptr, csr_src);
}